// Round 1
// baseline (4071.719 us; speedup 1.0000x reference)
//
#include <hip/hip_runtime.h>

#define HW 4096
#define NROWS 131072
#define MKEYS 512
#define DDIM 256

// ---- workspace layout (float offsets) ----
enum : int {
  WS_CMAXE = 0,                  // 512 uint (encoded col max)
  WS_CSUM  = 512,                // 512 f32 (col sum of exp(S))
  WS_CMAXF = 1024,               // 512 f32 (decoded col max)
  WS_INVC  = 1536,               // 512 f32 (1/csum)
  WS_RMAX  = 2048,               // N f32 (row max == top1 val)
  WS_FR    = WS_RMAX + NROWS,    // N f32 (exp(-rmax)/rowsum)
  WS_GIDX  = WS_FR + NROWS,      // N i32
  WS_G2    = WS_GIDX + NROWS,    // N i32
  WS_QUPD  = WS_G2 + NROWS,      // M*D f32 (segment sum accumulator)
  WS_LOSS  = WS_QUPD + MKEYS*DDIM, // 2 f32
};

__device__ __forceinline__ unsigned fenc(float f) {
  unsigned u = __float_as_uint(f);
  return (u & 0x80000000u) ? ~u : (u | 0x80000000u);
}
__device__ __forceinline__ float fdec(unsigned e) {
  return (e & 0x80000000u) ? __uint_as_float(e ^ 0x80000000u) : __uint_as_float(~e);
}
__device__ __forceinline__ bool better(float av, int ai, float bv, int bi) {
  return (av > bv) || (av == bv && ai < bi);
}

// ---- K0: init accumulators ----
__global__ void k_init(float* ws) {
  int i = blockIdx.x * 256 + threadIdx.x;
  if (i < 1024) ws[i] = 0.0f;                       // cmax_enc (0u) + csum
  if (i < MKEYS * DDIM + 2) ws[WS_QUPD + i] = 0.0f; // qupd + loss
}

// ---- K1: L2-normalize query over channel dim; write into out0 ch 0..255 ----
__global__ __launch_bounds__(256) void k_norm(const float* __restrict__ q,
                                              float* __restrict__ out0) {
  int n = blockIdx.x * 256 + threadIdx.x;
  int b = n >> 12, hw = n & 4095;
  const float* src = q + (size_t)b * DDIM * HW + hw;
  float ss = 0.0f;
#pragma unroll 8
  for (int c = 0; c < DDIM; ++c) { float v = src[(size_t)c * HW]; ss += v * v; }
  float inv = 1.0f / fmaxf(sqrtf(ss), 1e-12f);
  float* dst = out0 + (size_t)b * 512 * HW + hw;
#pragma unroll 8
  for (int c = 0; c < DDIM; ++c) dst[(size_t)c * HW] = src[(size_t)c * HW] * inv;
}

// ---- K2: S[n,m] = sum_c qn[n,c]*keys[m,c]  (fp32 tiled) ----
__global__ __launch_bounds__(256) void k_gemm1(const float* __restrict__ out0,
                                               const float* __restrict__ keys,
                                               float* __restrict__ S) {
  __shared__ float As[32][68]; // [c][n]
  __shared__ float Bs[32][68]; // [c][m]
  int t = threadIdx.x;
  int mt = blockIdx.x & 7, nt = blockIdx.x >> 3;
  int n0 = nt * 64, m0 = mt * 64;
  int b = n0 >> 12, hw0 = n0 & 4095;
  const float* Abase = out0 + (size_t)b * 512 * HW + hw0;
  float acc[4][4] = {};
  int tn = (t >> 4) * 4, tm = (t & 15) * 4;
  for (int k0 = 0; k0 < DDIM; k0 += 32) {
#pragma unroll
    for (int i = 0; i < 8; ++i) {
      int idx = t + i * 256;
      int c = idx >> 6, nn = idx & 63;
      As[c][nn] = Abase[(size_t)(k0 + c) * HW + nn];
    }
#pragma unroll
    for (int i = 0; i < 8; ++i) {
      int idx = t + i * 256;
      int c = idx & 31, mm = idx >> 5;
      Bs[c][mm] = keys[(m0 + mm) * DDIM + k0 + c];
    }
    __syncthreads();
#pragma unroll
    for (int k = 0; k < 32; ++k) {
      float4 a4 = *(const float4*)&As[k][tn];
      float4 b4 = *(const float4*)&Bs[k][tm];
      float av[4] = {a4.x, a4.y, a4.z, a4.w};
      float bv[4] = {b4.x, b4.y, b4.z, b4.w};
#pragma unroll
      for (int jn = 0; jn < 4; ++jn)
#pragma unroll
        for (int jm = 0; jm < 4; ++jm) acc[jn][jm] += av[jn] * bv[jm];
    }
    __syncthreads();
  }
#pragma unroll
  for (int j = 0; j < 4; ++j) {
    float4 v = make_float4(acc[j][0], acc[j][1], acc[j][2], acc[j][3]);
    *(float4*)&S[(size_t)(n0 + tn + j) * MKEYS + m0 + tm] = v;
  }
}

// ---- K3: per-row stats: max, top2 indices, softmax denominator ----
__global__ __launch_bounds__(256) void k_rowstats(const float* __restrict__ S,
                                                  float* __restrict__ rmax,
                                                  float* __restrict__ fr,
                                                  int* __restrict__ gidx,
                                                  int* __restrict__ g2idx) {
  int wave = threadIdx.x >> 6, lane = threadIdx.x & 63;
  int n = blockIdx.x * 4 + wave;
  const float* row = S + (size_t)n * MKEYS;
  float4 s0 = ((const float4*)row)[lane];
  float4 s1 = ((const float4*)row)[lane + 64];
  float vv[8] = {s0.x, s0.y, s0.z, s0.w, s1.x, s1.y, s1.z, s1.w};
  float v1 = -1e30f, v2 = -1e30f; int i1 = 0, i2 = 0;
#pragma unroll
  for (int j = 0; j < 8; ++j) {
    int idx = (j < 4) ? (4 * lane + j) : (256 + 4 * lane + j - 4);
    float val = vv[j];
    if (val > v1) { v2 = v1; i2 = i1; v1 = val; i1 = idx; }
    else if (val > v2) { v2 = val; i2 = idx; }
  }
  for (int off = 1; off < 64; off <<= 1) {
    float ov1 = __shfl_xor(v1, off); int oi1 = __shfl_xor(i1, off);
    float ov2 = __shfl_xor(v2, off); int oi2 = __shfl_xor(i2, off);
    if (better(ov1, oi1, v1, i1)) {
      if (better(v1, i1, ov2, oi2)) { v2 = v1; i2 = i1; } else { v2 = ov2; i2 = oi2; }
      v1 = ov1; i1 = oi1;
    } else {
      if (better(ov1, oi1, v2, i2)) { v2 = ov1; i2 = oi1; }
    }
  }
  float s = 0.0f;
#pragma unroll
  for (int j = 0; j < 8; ++j) s += __expf(vv[j] - v1);
  for (int off = 32; off; off >>= 1) s += __shfl_xor(s, off);
  if (lane == 0) {
    rmax[n] = v1;
    fr[n] = __expf(-v1) / s;
    gidx[n] = i1;
    g2idx[n] = i2;
  }
}

// ---- K3b: per-column max + sum of exp(S) ----
__global__ __launch_bounds__(256) void k_colstats(const float* __restrict__ S,
                                                  unsigned* __restrict__ cmaxe,
                                                  float* __restrict__ csum) {
  int t = threadIdx.x;
  size_t r0 = (size_t)blockIdx.x * 256;
  float mx0 = -1e30f, mx1 = -1e30f, sm0 = 0.0f, sm1 = 0.0f;
  for (int r = 0; r < 256; ++r) {
    float a = S[(r0 + r) * MKEYS + t];
    float b = S[(r0 + r) * MKEYS + t + 256];
    mx0 = fmaxf(mx0, a); sm0 += __expf(a);
    mx1 = fmaxf(mx1, b); sm1 += __expf(b);
  }
  atomicMax(&cmaxe[t], fenc(mx0));
  atomicMax(&cmaxe[t + 256], fenc(mx1));
  atomicAdd(&csum[t], sm0);
  atomicAdd(&csum[t + 256], sm1);
}

// ---- K3c: finalize column stats ----
__global__ void k_fincols(const unsigned* __restrict__ cmaxe, const float* __restrict__ csum,
                          float* __restrict__ cmaxf, float* __restrict__ invc) {
  int m = blockIdx.x * 256 + threadIdx.x;
  cmaxf[m] = fdec(cmaxe[m]);
  invc[m] = 1.0f / csum[m];
}

// ---- K4: write score_query, rewrite S in place as score_memory ----
__global__ __launch_bounds__(256) void k_softmax(float* __restrict__ S,
                                                 float* __restrict__ SQ,
                                                 const float* __restrict__ fr,
                                                 const float* __restrict__ invc) {
  int e = blockIdx.x * 256 + threadIdx.x; // float4 index
  int n = e >> 7;
  float4 s = ((const float4*)S)[e];
  float f = fr[n];
  float4 ic = ((const float4*)invc)[e & 127];
  float e0 = __expf(s.x), e1 = __expf(s.y), e2 = __expf(s.z), e3 = __expf(s.w);
  ((float4*)SQ)[e] = make_float4(e0 * ic.x, e1 * ic.y, e2 * ic.z, e3 * ic.w);
  ((float4*)S)[e]  = make_float4(e0 * f, e1 * f, e2 * f, e3 * f);
}

// ---- K5: concat_memory[n,c] = sum_m sm[n,m]*keys[m,c] -> out0 ch 256..511 ----
__global__ __launch_bounds__(256) void k_gemm2(const float* __restrict__ SM,
                                               const float* __restrict__ keys,
                                               float* __restrict__ out0) {
  __shared__ float As[32][68]; // [k][n]
  __shared__ float Bs[32][68]; // [k][c]
  int t = threadIdx.x;
  int ct = blockIdx.x & 3, nt = blockIdx.x >> 2;
  int n0 = nt * 64, c0 = ct * 64;
  float acc[4][4] = {};
  int tn = (t >> 4) * 4, tc = (t & 15) * 4;
  for (int k0 = 0; k0 < MKEYS; k0 += 32) {
#pragma unroll
    for (int i = 0; i < 8; ++i) {
      int idx = t + i * 256;
      int kk = idx & 31, nn = idx >> 5;
      As[kk][nn] = SM[(size_t)(n0 + nn) * MKEYS + k0 + kk];
    }
#pragma unroll
    for (int i = 0; i < 8; ++i) {
      int idx = t + i * 256;
      int kk = idx >> 6, cc = idx & 63;
      Bs[kk][cc] = keys[(k0 + kk) * DDIM + c0 + cc];
    }
    __syncthreads();
#pragma unroll
    for (int k = 0; k < 32; ++k) {
      float4 a4 = *(const float4*)&As[k][tn];
      float4 b4 = *(const float4*)&Bs[k][tc];
      float av[4] = {a4.x, a4.y, a4.z, a4.w};
      float bv[4] = {b4.x, b4.y, b4.z, b4.w};
#pragma unroll
      for (int jn = 0; jn < 4; ++jn)
#pragma unroll
        for (int jc = 0; jc < 4; ++jc) acc[jn][jc] += av[jn] * bv[jc];
    }
    __syncthreads();
  }
  int b = n0 >> 12, hw0 = n0 & 4095;
  float* dst = out0 + (size_t)b * 512 * HW + (size_t)(256 + c0 + tc) * HW + hw0 + tn;
#pragma unroll
  for (int jc = 0; jc < 4; ++jc) {
    float4 v = make_float4(acc[0][jc], acc[1][jc], acc[2][jc], acc[3][jc]);
    *(float4*)&dst[(size_t)jc * HW] = v;
  }
}

// ---- K6: losses + w + segment_sum via atomics ----
__global__ __launch_bounds__(256) void k_seg(const float* __restrict__ out0,
                                             const float* __restrict__ keys,
                                             const float* __restrict__ rmax,
                                             const float* __restrict__ cmaxf,
                                             const int* __restrict__ gidx,
                                             const int* __restrict__ g2idx,
                                             float* __restrict__ qupd,
                                             float* __restrict__ loss) {
  int n = blockIdx.x * 256 + threadIdx.x;
  int b = n >> 12, hw = n & 4095;
  const float* q = out0 + (size_t)b * 512 * HW + hw;
  int g = gidx[n], g2 = g2idx[n];
  float w = __expf(rmax[n] - cmaxf[g]);
  const float* kg = keys + g * DDIM;
  const float* kg2 = keys + g2 * DDIM;
  float gs = 0.0f, dp = 0.0f, dn = 0.0f;
#pragma unroll 4
  for (int c = 0; c < DDIM; ++c) {
    float qv = q[(size_t)c * HW];
    float a = qv - kg[c];
    gs += a * a;
    float p = a + 1e-6f; dp += p * p;
    float m2 = qv - kg2[c] + 1e-6f; dn += m2 * m2;
    atomicAdd(&qupd[g * DDIM + c], w * qv);
  }
  float h = fmaxf(sqrtf(dp) - sqrtf(dn) + 1.0f, 0.0f);
  int lane = threadIdx.x & 63;
  for (int off = 32; off; off >>= 1) {
    gs += __shfl_down(gs, off);
    h += __shfl_down(h, off);
  }
  if (lane == 0) { atomicAdd(&loss[0], gs); atomicAdd(&loss[1], h); }
}

// ---- K7: updated_memory + loss finalize ----
__global__ __launch_bounds__(256) void k_upd(const float* __restrict__ qupd,
                                             const float* __restrict__ keys,
                                             float* __restrict__ out1,
                                             const float* __restrict__ loss,
                                             float* __restrict__ out4,
                                             float* __restrict__ out5) {
  int wave = threadIdx.x >> 6, lane = threadIdx.x & 63;
  int m = blockIdx.x * 4 + wave;
  float4 a = ((const float4*)(qupd + m * DDIM))[lane];
  float4 k = ((const float4*)(keys + m * DDIM))[lane];
  float4 s = make_float4(a.x + k.x, a.y + k.y, a.z + k.z, a.w + k.w);
  float ss = s.x * s.x + s.y * s.y + s.z * s.z + s.w * s.w;
  for (int off = 32; off; off >>= 1) ss += __shfl_xor(ss, off);
  float inv = 1.0f / fmaxf(sqrtf(ss), 1e-12f);
  ((float4*)(out1 + m * DDIM))[lane] = make_float4(s.x * inv, s.y * inv, s.z * inv, s.w * inv);
  if (blockIdx.x == 0 && threadIdx.x == 0) {
    out4[0] = loss[0] / (131072.0f * 256.0f);
    out5[0] = loss[1] / 131072.0f;
  }
}

extern "C" void kernel_launch(void* const* d_in, const int* in_sizes, int n_in,
                              void* d_out, int out_size, void* d_ws, size_t ws_size,
                              hipStream_t stream) {
  const float* query = (const float*)d_in[0];
  const float* keys  = (const float*)d_in[1];
  float* out0 = (float*)d_out;                 // updated_query (32,512,64,64)
  float* out1 = out0 + (size_t)67108864;       // updated_memory (512,256)
  float* out2 = out1 + 131072;                 // score_query (N,512)
  float* out3 = out2 + (size_t)67108864;       // score_memory (N,512) — used as raw-S scratch first
  float* out4 = out3 + (size_t)67108864;       // gathering_loss
  float* out5 = out4 + 1;                      // spreading_loss
  float* ws = (float*)d_ws;

  hipLaunchKernelGGL(k_init, dim3(517), dim3(256), 0, stream, ws);
  hipLaunchKernelGGL(k_norm, dim3(512), dim3(256), 0, stream, query, out0);
  hipLaunchKernelGGL(k_gemm1, dim3(16384), dim3(256), 0, stream, out0, keys, out3);
  hipLaunchKernelGGL(k_rowstats, dim3(32768), dim3(256), 0, stream, out3,
                     ws + WS_RMAX, ws + WS_FR, (int*)(ws + WS_GIDX), (int*)(ws + WS_G2));
  hipLaunchKernelGGL(k_colstats, dim3(512), dim3(256), 0, stream, out3,
                     (unsigned*)(ws + WS_CMAXE), ws + WS_CSUM);
  hipLaunchKernelGGL(k_fincols, dim3(2), dim3(256), 0, stream,
                     (const unsigned*)(ws + WS_CMAXE), ws + WS_CSUM, ws + WS_CMAXF, ws + WS_INVC);
  hipLaunchKernelGGL(k_softmax, dim3(65536), dim3(256), 0, stream, out3, out2,
                     ws + WS_FR, ws + WS_INVC);
  hipLaunchKernelGGL(k_gemm2, dim3(8192), dim3(256), 0, stream, out3, keys, out0);
  hipLaunchKernelGGL(k_seg, dim3(512), dim3(256), 0, stream, out0, keys,
                     ws + WS_RMAX, ws + WS_CMAXF, (const int*)(ws + WS_GIDX),
                     (const int*)(ws + WS_G2), ws + WS_QUPD, ws + WS_LOSS);
  hipLaunchKernelGGL(k_upd, dim3(128), dim3(256), 0, stream, ws + WS_QUPD, keys,
                     out1, ws + WS_LOSS, out4, out5);
}